// Round 2
// baseline (157.233 us; speedup 1.0000x reference)
//
#include <hip/hip_runtime.h>

// KANLayer: B=1024, I=64, O=64, H=32. ALL I/O float32 (per reference).
// out[b,o] = sum_i [ bw[o,i]*leaky(x[b,i]) + lw[o,i]*( sum_k W3[o,i,k]*h2 + b3[o,i] ) ]
//   h1[h] = leaky(x[b,i]*W1[o,i,h] + b1[o,i,h])
//   h2[k] = leaky(sum_h h1[h]*W2[o,i,k,h] + b2[o,i,k])
// Strategy: per block = (128 batch rows, one o). Inner loop over i.
// h1 built in registers (f32), converted to bf16 A-frags; W2 converted to
// bf16 B-frags; mfma_f32_16x16x32_bf16 does the 32-wide h contraction with
// f32 accumulation; b2 folded into the MFMA C operand.

#define H_  32
#define NI  64
#define NO  64
#define NB  1024
#define ROWS 128          // batch rows per block (4 waves x 2 mtiles x 16)
#define XSTR 68           // LDS row stride (f32): 272B = 17*16B aligned, 2-way-max banks (free)

typedef float  floatx4 __attribute__((ext_vector_type(4)));
typedef short  shortx8 __attribute__((ext_vector_type(8)));   // 8 bf16 = 4 VGPRs

__device__ inline short f2bf(float f) {
    unsigned int u = __float_as_uint(f);
    u += 0x7FFFu + ((u >> 16) & 1u);   // RNE; inputs are bounded, no NaN/Inf path
    return (short)(u >> 16);
}
__device__ inline float leaky(float v) { return fmaxf(v, 0.01f * v); }

__global__ __launch_bounds__(256, 2)
void kan_kernel(const float* __restrict__ x,
                const float* __restrict__ W1,
                const float* __restrict__ b1,
                const float* __restrict__ W2,
                const float* __restrict__ b2,
                const float* __restrict__ W3,
                const float* __restrict__ b3,
                const float* __restrict__ lw,
                const float* __restrict__ bw,
                float* __restrict__ out)
{
    __shared__ float xs[ROWS * XSTR];
    __shared__ float rc[ROWS];

    const int t    = threadIdx.x;
    const int o    = blockIdx.y;
    const int row0 = blockIdx.x * ROWS;

    // ---- stage x[row0 : row0+128, 0:64] into LDS (coalesced 16B loads) ----
    const float* xsrc = x + (size_t)row0 * NI;
    #pragma unroll
    for (int v = 0; v < 8; ++v) {
        int fe = (v * 256 + t) * 4;          // flat element index (mult of 4)
        int r  = fe >> 6, c = fe & 63;
        *(float4*)(&xs[r * XSTR + c]) = *(const float4*)(&xsrc[fe]);
    }
    __syncthreads();

    // ---- per-row constants: rc[r] = sum_i [ bw*leaky(x) + lw*b3 ] ----
    if (t < ROWS) {
        float s = 0.f;
        for (int i = 0; i < NI; ++i) {
            float xv = xs[t * XSTR + i];
            s += bw[o * NI + i] * leaky(xv) + lw[o * NI + i] * b3[o * NI + i];
        }
        rc[t] = s;
    }

    const int lane = t & 63;
    const int wave = t >> 6;
    const int col  = lane & 15;      // MFMA n-index (h2 k-slot) / C col
    const int kh   = lane >> 4;      // quad -> contraction chunk
    const int koff = kh * 8;
    const int wrow = wave * 32;      // wave's local row base (2 mtiles of 16)

    float pacc[2][4] = {{0.f,0.f,0.f,0.f},{0.f,0.f,0.f,0.f}};

    for (int i = 0; i < NI; ++i) {
        const int ei = o * NI + i;

        // W1/b1: this lane's 8-wide h-chunk (f32, 2x float4 each)
        const float* w1p = W1 + (size_t)ei * H_ + koff;
        const float* b1p = b1 + (size_t)ei * H_ + koff;
        floatx4 w1a = *(const floatx4*)(w1p);
        floatx4 w1b = *(const floatx4*)(w1p + 4);
        floatx4 b1a = *(const floatx4*)(b1p);
        floatx4 b1b = *(const floatx4*)(b1p + 4);

        // B-frags: lane holds W2[o,i, n=col(+16), h=koff..koff+7]
        const float* w2p0 = W2 + ((size_t)ei * H_ + col     ) * H_ + koff;
        const float* w2p1 = W2 + ((size_t)ei * H_ + col + 16) * H_ + koff;
        floatx4 w2a0 = *(const floatx4*)(w2p0);
        floatx4 w2b0 = *(const floatx4*)(w2p0 + 4);
        floatx4 w2a1 = *(const floatx4*)(w2p1);
        floatx4 w2b1 = *(const floatx4*)(w2p1 + 4);
        shortx8 bf0, bf1;
        #pragma unroll
        for (int j = 0; j < 4; ++j) {
            bf0[j]     = f2bf(w2a0[j]);
            bf0[j + 4] = f2bf(w2b0[j]);
            bf1[j]     = f2bf(w2a1[j]);
            bf1[j + 4] = f2bf(w2b1[j]);
        }

        float b2c0 = b2[(size_t)ei * H_ + col];
        float b2c1 = b2[(size_t)ei * H_ + col + 16];
        float lwv  = lw[ei];                          // wave-uniform -> scalar
        float w3e0 = lwv * W3[(size_t)ei * H_ + col];
        float w3e1 = lwv * W3[(size_t)ei * H_ + col + 16];

        #pragma unroll
        for (int m = 0; m < 2; ++m) {
            // A-frag: h1 for batch row (wrow + m*16 + col), h-chunk koff..+7
            float xv = xs[(wrow + m * 16 + col) * XSTR + i];
            shortx8 af;
            #pragma unroll
            for (int j = 0; j < 4; ++j) {
                float h1a = fmaf(xv, w1a[j], b1a[j]);
                float h1b = fmaf(xv, w1b[j], b1b[j]);
                af[j]     = f2bf(leaky(h1a));
                af[j + 4] = f2bf(leaky(h1b));
            }
            floatx4 c0 = {b2c0, b2c0, b2c0, b2c0};    // fold b2 into C init
            floatx4 c1 = {b2c1, b2c1, b2c1, b2c1};
            c0 = __builtin_amdgcn_mfma_f32_16x16x32_bf16(af, bf0, c0, 0, 0, 0);
            c1 = __builtin_amdgcn_mfma_f32_16x16x32_bf16(af, bf1, c1, 0, 0, 0);
            #pragma unroll
            for (int r = 0; r < 4; ++r) {
                pacc[m][r] += leaky(c0[r]) * w3e0 + leaky(c1[r]) * w3e1;
            }
        }
    }

    __syncthreads();   // rc written by waves 0/1; read cross-wave below

    // ---- reduce over the 16 column-lanes (n of h2), write out[b,o] ----
    #pragma unroll
    for (int m = 0; m < 2; ++m) {
        #pragma unroll
        for (int r = 0; r < 4; ++r) {
            float v = pacc[m][r];
            v += __shfl_xor(v, 1, 64);
            v += __shfl_xor(v, 2, 64);
            v += __shfl_xor(v, 4, 64);
            v += __shfl_xor(v, 8, 64);
            if (col == 0) {
                int rl = wrow + m * 16 + kh * 4 + r;  // C-layout: row=(lane>>4)*4+reg
                out[(size_t)(row0 + rl) * NO + o] = v + rc[rl];
            }
        }
    }
}

extern "C" void kernel_launch(void* const* d_in, const int* in_sizes, int n_in,
                              void* d_out, int out_size, void* d_ws, size_t ws_size,
                              hipStream_t stream) {
    const float* x  = (const float*)d_in[0];
    const float* W1 = (const float*)d_in[1];
    const float* b1 = (const float*)d_in[2];
    const float* W2 = (const float*)d_in[3];
    const float* b2 = (const float*)d_in[4];
    const float* W3 = (const float*)d_in[5];
    const float* b3 = (const float*)d_in[6];
    const float* lw = (const float*)d_in[7];
    const float* bw = (const float*)d_in[8];
    float* out = (float*)d_out;

    dim3 grid(NB / ROWS, NO);
    kan_kernel<<<grid, dim3(256), 0, stream>>>(x, W1, b1, W2, b2, W3, b3, lw, bw, out);
}